// Round 15
// baseline (39.177 us; speedup 1.0000x reference)
//
#include <hip/hip_runtime.h>

// DynamicMaskHead v15: v14 (single-launch, verified absmax 0.046875) +
// (a) s_setprio(1) around MFMA stage clusters -- post-barrier the 4 waves
//     are independent (attn-like regime where setprio measured +4-7%),
// (b) 2-deep LDS fragment ping-pong: instance i+1's five ds_read_b128
//     issue before instance i's compute, hiding LDS latency.
// Structure: block = 4 waves x 80 px = 320 px; grid = 128 x 4 x NSPLIT(2)
// = 1024 blocks = 4 blocks/CU; in-block packing of 8 instances' fragments
// into 40960 B LDS (160 KiB/CU at 4 blocks); stage-wise all-MFMA loop:
//   acc = ca*coords + W0a*X + W0b*X ; relu/cvt ; a1b MFMA (b1 channel);
//   relu/cvt ; a2r MFMA (row-replicated w2 + b2 channel) -> acc[0] = out.

#define CIN  64
#define HH   160
#define WW   256
#define HWSZ (HH * WW)
#define PP   1361
#define MASK_BIAS_SHIFT 2.19f
#define PKF  1280              // floats per instance in LDS block (5120 B)
#define NSPLIT 2               // instance split across gridDim.z
#define NT   5                 // 16-px tiles per wave (80 px)
#define MAXI 8                 // max instances per split (16 / NSPLIT)
#define BLKPX (16 * NT * 4)    // 320 px per block

typedef short short8 __attribute__((ext_vector_type(8)));
typedef float f32x4  __attribute__((ext_vector_type(4)));

union BF8 { short8 s; __bf16 b[8]; };

__device__ inline __bf16 bhi(float v) { return (__bf16)v; }
__device__ inline __bf16 blo(float v) { return (__bf16)(v - (float)(__bf16)v); }

// LDS float offsets per instance slot:
//   0: a00 (W0 x-ch 0..31)   256: a01 (x-ch 32..63)   512: a1b (W1 + b1 ch)
//   768: a2r (replicated w2 + b2 ch)   1024: ca (coord/b0 ch)

__device__ __forceinline__ void pack_one(const float* __restrict__ pw,
                                         int lane, float* __restrict__ dst)
{
    const int col = lane & 15;
    const int g   = lane >> 4;
    const __bf16 z = (__bf16)0.f;

    BF8 a00, a01;
#pragma unroll
    for (int j = 0; j < 8; ++j) {
        a00.b[j] = (__bf16)pw[col * 66 + 2 +      g * 8 + j];
        a01.b[j] = (__bf16)pw[col * 66 + 2 + 32 + g * 8 + j];
    }

    BF8 a1b;                                   // W1 (k=0..15) + b1 bias channel
#pragma unroll
    for (int j = 0; j < 4; ++j)
        a1b.b[j] = (__bf16)pw[1056 + col * 16 + g * 4 + j];
    {
        const float b1 = pw[1344 + col];
        a1b.b[4] = (g == 0) ? bhi(b1) : z;
        a1b.b[5] = (g == 0) ? blo(b1) : z;
        a1b.b[6] = z;  a1b.b[7] = z;
    }

    BF8 a2r;                    // w2 replicated across rows + b2 bias channel
#pragma unroll
    for (int j = 0; j < 4; ++j) a2r.b[j] = (__bf16)pw[1312 + g * 4 + j];
    {
        const float b2 = pw[1360] - MASK_BIAS_SHIFT;
        a2r.b[4] = (g == 0) ? bhi(b2) : z;
        a2r.b[5] = (g == 0) ? blo(b2) : z;
        a2r.b[6] = z;  a2r.b[7] = z;
    }

    BF8 ca;   // [wx_hi,wx_lo,wy_hi,wy_lo,b0_hi,b0_lo,0,0] on g==0 lanes
    {
        const float wx = pw[col * 66 + 0];
        const float wy = pw[col * 66 + 1];
        const float b0 = pw[1328 + col];
        ca.b[0] = (g == 0) ? bhi(wx) : z;
        ca.b[1] = (g == 0) ? blo(wx) : z;
        ca.b[2] = (g == 0) ? bhi(wy) : z;
        ca.b[3] = (g == 0) ? blo(wy) : z;
        ca.b[4] = (g == 0) ? bhi(b0) : z;
        ca.b[5] = (g == 0) ? blo(b0) : z;
        ca.b[6] = z; ca.b[7] = z;
    }

    ((short8*)(dst       ))[lane] = a00.s;
    ((short8*)(dst +  256))[lane] = a01.s;
    ((short8*)(dst +  512))[lane] = a1b.s;
    ((short8*)(dst +  768))[lane] = a2r.s;
    ((short8*)(dst + 1024))[lane] = ca.s;
}

struct Frag { short8 ca, a00, a01, a1b, a2r; };

__device__ __forceinline__ void frag_ld(const short8* __restrict__ fp,
                                        int lane, Frag& f)
{
    f.ca  = fp[256 + lane];
    f.a00 = fp[       lane];
    f.a01 = fp[ 64 + lane];
    f.a1b = fp[128 + lane];
    f.a2r = fp[192 + lane];
}

__global__ __launch_bounds__(256, 4) void mask_head_v15(
    const float* __restrict__ x,
    const float* __restrict__ params,
    const int*   __restrict__ num_ins,
    float*       __restrict__ out,
    int N, int T)
{
    __shared__ __align__(16) float plds[MAXI][PKF];   // 40960 B

    const int tid  = threadIdx.x;
    const int wave = tid >> 6;
    const int lane = tid & 63;
    const int col  = lane & 15;
    const int g    = lane >> 4;
    const int n    = blockIdx.y;
    const int s    = blockIdx.z;
    const int pxw  = blockIdx.x * BLKPX + wave * (16 * NT);

    // instance range for this image (repeat-pad on last image)
    int t0 = 0;
    for (int j = 0; j < n; ++j) t0 += num_ins[j];
    int t1 = t0 + num_ins[n];
    if (n == N - 1) t1 = T;
    if (t1 > T) t1 = T;
    t0 = __builtin_amdgcn_readfirstlane(t0);
    t1 = __builtin_amdgcn_readfirstlane(t1);
    const int M = t1 - t0;

    // instances of this split: t = t0 + s + NSPLIT*i, i in [0, mloc)
    int mloc = (M - s + NSPLIT - 1) / NSPLIT;
    if (mloc < 0) mloc = 0;
    if (mloc > MAXI) mloc = MAXI;

    // ---- in-block packing: wave w packs instance slots {w, w+4}
#pragma unroll
    for (int k = 0; k < 2; ++k) {
        const int i = wave + k * 4;
        if (i < mloc) {
            const int t = t0 + s + NSPLIT * i;
            pack_one(params + (size_t)t * PP, lane, plds[i]);
        }
    }

    // x fragments: 80 px x 64 ch (40 VGPR); latency overlaps packing
    BF8 xb[NT][2];
    const float* xbase = x + (size_t)n * CIN * HWSZ + pxw + col;
#pragma unroll
    for (int nt = 0; nt < NT; ++nt)
#pragma unroll
        for (int c = 0; c < 2; ++c)
#pragma unroll
            for (int j = 0; j < 8; ++j) {
                const int ch = c * 32 + g * 8 + j;
                xb[nt][c].b[j] = (__bf16)xbase[(size_t)ch * HWSZ + nt * 16];
            }

    // coordinate B-fragments (instance-independent): [xf,xf,yf,yf,1,1,0,0]
    BF8 b2c[NT];
#pragma unroll
    for (int nt = 0; nt < NT; ++nt) {
        const int px = pxw + nt * 16 + col;
        const __bf16 xfb = (__bf16)(float)(px & (WW - 1));
        const __bf16 yfb = (__bf16)(float)(px >> 8);
        b2c[nt].b[0] = xfb; b2c[nt].b[1] = xfb;
        b2c[nt].b[2] = yfb; b2c[nt].b[3] = yfb;
        b2c[nt].b[4] = (__bf16)1.f; b2c[nt].b[5] = (__bf16)1.f;
        b2c[nt].b[6] = (__bf16)0.f; b2c[nt].b[7] = (__bf16)0.f;
    }

    const __bf16 one = (__bf16)1.f, zero = (__bf16)0.f;
    __syncthreads();   // all packing visible

    if (mloc <= 0) return;

    // ---- instance loop with 2-deep fragment ping-pong + setprio on MFMA
    Frag fA, fB;
    frag_ld((const short8*)plds[0], lane, fA);

    for (int i = 0; i < mloc; ++i) {
        // prefetch next instance's fragments before computing this one
        if (i + 1 < mloc) frag_ld((const short8*)plds[i + 1], lane,
                                  (i & 1) ? fA : fB);
        const Frag& f = (i & 1) ? fB : fA;
        const int t = t0 + s + NSPLIT * i;

        f32x4 acc[NT];
        __builtin_amdgcn_s_setprio(1);
#pragma unroll
        for (int nt = 0; nt < NT; ++nt) {
            f32x4 z4 = {0.f, 0.f, 0.f, 0.f};
            acc[nt] = __builtin_amdgcn_mfma_f32_16x16x32_bf16(f.ca, b2c[nt].s, z4, 0, 0, 0);
        }
#pragma unroll
        for (int nt = 0; nt < NT; ++nt)
            acc[nt] = __builtin_amdgcn_mfma_f32_16x16x32_bf16(f.a00, xb[nt][0].s, acc[nt], 0, 0, 0);
#pragma unroll
        for (int nt = 0; nt < NT; ++nt)
            acc[nt] = __builtin_amdgcn_mfma_f32_16x16x32_bf16(f.a01, xb[nt][1].s, acc[nt], 0, 0, 0);
        __builtin_amdgcn_s_setprio(0);

        BF8 h[NT];
#pragma unroll
        for (int nt = 0; nt < NT; ++nt) {
#pragma unroll
            for (int j = 0; j < 4; ++j) h[nt].b[j] = (__bf16)fmaxf(acc[nt][j], 0.f);
            h[nt].b[4] = one; h[nt].b[5] = one; h[nt].b[6] = zero; h[nt].b[7] = zero;
        }

        __builtin_amdgcn_s_setprio(1);
#pragma unroll
        for (int nt = 0; nt < NT; ++nt) {
            f32x4 z4 = {0.f, 0.f, 0.f, 0.f};
            acc[nt] = __builtin_amdgcn_mfma_f32_16x16x32_bf16(f.a1b, h[nt].s, z4, 0, 0, 0);
        }
        __builtin_amdgcn_s_setprio(0);

#pragma unroll
        for (int nt = 0; nt < NT; ++nt) {
#pragma unroll
            for (int j = 0; j < 4; ++j) h[nt].b[j] = (__bf16)fmaxf(acc[nt][j], 0.f);
            h[nt].b[4] = one; h[nt].b[5] = one; h[nt].b[6] = zero; h[nt].b[7] = zero;
        }

        __builtin_amdgcn_s_setprio(1);
#pragma unroll
        for (int nt = 0; nt < NT; ++nt) {
            f32x4 z4 = {0.f, 0.f, 0.f, 0.f};
            acc[nt] = __builtin_amdgcn_mfma_f32_16x16x32_bf16(f.a2r, h[nt].s, z4, 0, 0, 0);
        }
        __builtin_amdgcn_s_setprio(0);

        float oval = 0.f, t4 = 0.f;
#pragma unroll
        for (int nt = 0; nt < NT; ++nt) {
            if (nt == g)  oval = acc[nt][0];
            if (nt == 4)  t4   = acc[nt][0];
        }
        float* const op = out + (size_t)t * HWSZ + pxw;
        op[lane] = oval;                      // 64-lane coalesced (tiles 0-3)
        if (g == 0) op[64 + col] = t4;        // 16-lane store (tile 4)
    }
}

extern "C" void kernel_launch(void* const* d_in, const int* in_sizes, int n_in,
                              void* d_out, int out_size, void* d_ws, size_t ws_size,
                              hipStream_t stream) {
    const float* x      = (const float*)d_in[0];
    const float* params = (const float*)d_in[1];
    const int*   nins   = (const int*)d_in[2];
    float*       out    = (float*)d_out;

    const int N = in_sizes[2];            // images
    const int T = in_sizes[1] / PP;       // total instances (param rows)

    dim3 grid(HWSZ / BLKPX, N, NSPLIT);   // 128 x 4 x 2 = 1024 blocks
    mask_head_v15<<<grid, dim3(256), 0, stream>>>(x, params, nins, out, N, T);
}

// Round 16
// 27.708 us; speedup vs baseline: 1.4139x; 1.4139x over previous
//
#include <hip/hip_runtime.h>

// DynamicMaskHead v16: exact v14 structure (single-launch, in-block param
// packing, stage-wise all-MFMA loop, verified absmax 0.046875) + ONE change:
// s_setprio(1)/(0) around the three MFMA stage clusters. v15's regression
// was the runtime-selected Frag reference (VGPR collapsed to 64, compiler
// emitted conditional struct moves); that is reverted entirely.
// Block = 4 waves x 80 px = 320 px; grid = 128 x 4 images x NSPLIT(2)
// = 1024 blocks = 4 blocks/CU; LDS 40960 B = 160 KiB/CU at 4 blocks.
// Per (instance, 16-px tile): 5 MFMAs, zero shuffles:
//   acc = ca*coords + W0a*X + W0b*X ; relu/cvt ; a1b MFMA (b1 channel);
//   relu/cvt ; a2r MFMA (row-replicated w2 + b2 channel) -> acc[0] = out.

#define CIN  64
#define HH   160
#define WW   256
#define HWSZ (HH * WW)
#define PP   1361
#define MASK_BIAS_SHIFT 2.19f
#define PKF  1280              // floats per instance in LDS block (5120 B)
#define NSPLIT 2               // instance split across gridDim.z
#define NT   5                 // 16-px tiles per wave (80 px)
#define MAXI 8                 // max instances per split (16 / NSPLIT)
#define BLKPX (16 * NT * 4)    // 320 px per block

typedef short short8 __attribute__((ext_vector_type(8)));
typedef float f32x4  __attribute__((ext_vector_type(4)));

union BF8 { short8 s; __bf16 b[8]; };

__device__ inline __bf16 bhi(float v) { return (__bf16)v; }
__device__ inline __bf16 blo(float v) { return (__bf16)(v - (float)(__bf16)v); }

// LDS float offsets per instance slot:
//   0: a00 (W0 x-ch 0..31)   256: a01 (x-ch 32..63)   512: a1b (W1 + b1 ch)
//   768: a2r (replicated w2 + b2 ch)   1024: ca (coord/b0 ch)

__device__ __forceinline__ void pack_one(const float* __restrict__ pw,
                                         int lane, float* __restrict__ dst)
{
    const int col = lane & 15;
    const int g   = lane >> 4;
    const __bf16 z = (__bf16)0.f;

    BF8 a00, a01;
#pragma unroll
    for (int j = 0; j < 8; ++j) {
        a00.b[j] = (__bf16)pw[col * 66 + 2 +      g * 8 + j];
        a01.b[j] = (__bf16)pw[col * 66 + 2 + 32 + g * 8 + j];
    }

    BF8 a1b;                                   // W1 (k=0..15) + b1 bias channel
#pragma unroll
    for (int j = 0; j < 4; ++j)
        a1b.b[j] = (__bf16)pw[1056 + col * 16 + g * 4 + j];
    {
        const float b1 = pw[1344 + col];
        a1b.b[4] = (g == 0) ? bhi(b1) : z;
        a1b.b[5] = (g == 0) ? blo(b1) : z;
        a1b.b[6] = z;  a1b.b[7] = z;
    }

    BF8 a2r;                    // w2 replicated across rows + b2 bias channel
#pragma unroll
    for (int j = 0; j < 4; ++j) a2r.b[j] = (__bf16)pw[1312 + g * 4 + j];
    {
        const float b2 = pw[1360] - MASK_BIAS_SHIFT;
        a2r.b[4] = (g == 0) ? bhi(b2) : z;
        a2r.b[5] = (g == 0) ? blo(b2) : z;
        a2r.b[6] = z;  a2r.b[7] = z;
    }

    BF8 ca;   // [wx_hi,wx_lo,wy_hi,wy_lo,b0_hi,b0_lo,0,0] on g==0 lanes
    {
        const float wx = pw[col * 66 + 0];
        const float wy = pw[col * 66 + 1];
        const float b0 = pw[1328 + col];
        ca.b[0] = (g == 0) ? bhi(wx) : z;
        ca.b[1] = (g == 0) ? blo(wx) : z;
        ca.b[2] = (g == 0) ? bhi(wy) : z;
        ca.b[3] = (g == 0) ? blo(wy) : z;
        ca.b[4] = (g == 0) ? bhi(b0) : z;
        ca.b[5] = (g == 0) ? blo(b0) : z;
        ca.b[6] = z; ca.b[7] = z;
    }

    ((short8*)(dst       ))[lane] = a00.s;
    ((short8*)(dst +  256))[lane] = a01.s;
    ((short8*)(dst +  512))[lane] = a1b.s;
    ((short8*)(dst +  768))[lane] = a2r.s;
    ((short8*)(dst + 1024))[lane] = ca.s;
}

__global__ __launch_bounds__(256, 4) void mask_head_v16(
    const float* __restrict__ x,
    const float* __restrict__ params,
    const int*   __restrict__ num_ins,
    float*       __restrict__ out,
    int N, int T)
{
    __shared__ __align__(16) float plds[MAXI][PKF];   // 40960 B

    const int tid  = threadIdx.x;
    const int wave = tid >> 6;
    const int lane = tid & 63;
    const int col  = lane & 15;
    const int g    = lane >> 4;
    const int n    = blockIdx.y;
    const int s    = blockIdx.z;
    const int pxw  = blockIdx.x * BLKPX + wave * (16 * NT);

    // instance range for this image (repeat-pad on last image)
    int t0 = 0;
    for (int j = 0; j < n; ++j) t0 += num_ins[j];
    int t1 = t0 + num_ins[n];
    if (n == N - 1) t1 = T;
    if (t1 > T) t1 = T;
    t0 = __builtin_amdgcn_readfirstlane(t0);
    t1 = __builtin_amdgcn_readfirstlane(t1);
    const int M = t1 - t0;

    // instances of this split: t = t0 + s + NSPLIT*i, i in [0, mloc)
    int mloc = (M - s + NSPLIT - 1) / NSPLIT;
    if (mloc < 0) mloc = 0;
    if (mloc > MAXI) mloc = MAXI;

    // ---- in-block packing: wave w packs instance slots {w, w+4}
#pragma unroll
    for (int k = 0; k < 2; ++k) {
        const int i = wave + k * 4;
        if (i < mloc) {
            const int t = t0 + s + NSPLIT * i;
            pack_one(params + (size_t)t * PP, lane, plds[i]);
        }
    }

    // x fragments: 80 px x 64 ch (40 VGPR); global-load latency overlaps
    // the packing (no LDS dependency until the barrier)
    BF8 xb[NT][2];
    const float* xbase = x + (size_t)n * CIN * HWSZ + pxw + col;
#pragma unroll
    for (int nt = 0; nt < NT; ++nt)
#pragma unroll
        for (int c = 0; c < 2; ++c)
#pragma unroll
            for (int j = 0; j < 8; ++j) {
                const int ch = c * 32 + g * 8 + j;
                xb[nt][c].b[j] = (__bf16)xbase[(size_t)ch * HWSZ + nt * 16];
            }

    // coordinate B-fragments (instance-independent): [xf,xf,yf,yf,1,1,0,0]
    BF8 b2c[NT];
#pragma unroll
    for (int nt = 0; nt < NT; ++nt) {
        const int px = pxw + nt * 16 + col;
        const __bf16 xfb = (__bf16)(float)(px & (WW - 1));
        const __bf16 yfb = (__bf16)(float)(px >> 8);
        b2c[nt].b[0] = xfb; b2c[nt].b[1] = xfb;
        b2c[nt].b[2] = yfb; b2c[nt].b[3] = yfb;
        b2c[nt].b[4] = (__bf16)1.f; b2c[nt].b[5] = (__bf16)1.f;
        b2c[nt].b[6] = (__bf16)0.f; b2c[nt].b[7] = (__bf16)0.f;
    }

    const __bf16 one = (__bf16)1.f, zero = (__bf16)0.f;
    __syncthreads();   // all packing visible

    // ---- instance loop: stage-wise across all 5 tiles (5-way chain ILP)
    for (int i = 0; i < mloc; ++i) {
        const int t = t0 + s + NSPLIT * i;
        const short8* fp = (const short8*)plds[i];

        short8 ca  = fp[256 + lane];
        short8 a00 = fp[       lane];
        short8 a01 = fp[ 64 + lane];

        f32x4 acc[NT];
        __builtin_amdgcn_s_setprio(1);
#pragma unroll
        for (int nt = 0; nt < NT; ++nt) {
            f32x4 z4 = {0.f, 0.f, 0.f, 0.f};
            acc[nt] = __builtin_amdgcn_mfma_f32_16x16x32_bf16(ca, b2c[nt].s, z4, 0, 0, 0);
        }
#pragma unroll
        for (int nt = 0; nt < NT; ++nt)
            acc[nt] = __builtin_amdgcn_mfma_f32_16x16x32_bf16(a00, xb[nt][0].s, acc[nt], 0, 0, 0);
#pragma unroll
        for (int nt = 0; nt < NT; ++nt)
            acc[nt] = __builtin_amdgcn_mfma_f32_16x16x32_bf16(a01, xb[nt][1].s, acc[nt], 0, 0, 0);
        __builtin_amdgcn_s_setprio(0);

        BF8 h[NT];
#pragma unroll
        for (int nt = 0; nt < NT; ++nt) {
#pragma unroll
            for (int j = 0; j < 4; ++j) h[nt].b[j] = (__bf16)fmaxf(acc[nt][j], 0.f);
            h[nt].b[4] = one; h[nt].b[5] = one; h[nt].b[6] = zero; h[nt].b[7] = zero;
        }

        short8 a1b = fp[128 + lane];
        __builtin_amdgcn_s_setprio(1);
#pragma unroll
        for (int nt = 0; nt < NT; ++nt) {
            f32x4 z4 = {0.f, 0.f, 0.f, 0.f};
            acc[nt] = __builtin_amdgcn_mfma_f32_16x16x32_bf16(a1b, h[nt].s, z4, 0, 0, 0);
        }
        __builtin_amdgcn_s_setprio(0);

#pragma unroll
        for (int nt = 0; nt < NT; ++nt) {
#pragma unroll
            for (int j = 0; j < 4; ++j) h[nt].b[j] = (__bf16)fmaxf(acc[nt][j], 0.f);
            h[nt].b[4] = one; h[nt].b[5] = one; h[nt].b[6] = zero; h[nt].b[7] = zero;
        }

        short8 a2r = fp[192 + lane];
        __builtin_amdgcn_s_setprio(1);
#pragma unroll
        for (int nt = 0; nt < NT; ++nt) {
            f32x4 z4 = {0.f, 0.f, 0.f, 0.f};
            acc[nt] = __builtin_amdgcn_mfma_f32_16x16x32_bf16(a2r, h[nt].s, z4, 0, 0, 0);
        }
        __builtin_amdgcn_s_setprio(0);

        float oval = 0.f, t4 = 0.f;
#pragma unroll
        for (int nt = 0; nt < NT; ++nt) {
            if (nt == g)  oval = acc[nt][0];
            if (nt == 4)  t4   = acc[nt][0];
        }
        float* const op = out + (size_t)t * HWSZ + pxw;
        op[lane] = oval;                      // 64-lane coalesced (tiles 0-3)
        if (g == 0) op[64 + col] = t4;        // 16-lane store (tile 4)
    }
}

extern "C" void kernel_launch(void* const* d_in, const int* in_sizes, int n_in,
                              void* d_out, int out_size, void* d_ws, size_t ws_size,
                              hipStream_t stream) {
    const float* x      = (const float*)d_in[0];
    const float* params = (const float*)d_in[1];
    const int*   nins   = (const int*)d_in[2];
    float*       out    = (float*)d_out;

    const int N = in_sizes[2];            // images
    const int T = in_sizes[1] / PP;       // total instances (param rows)

    dim3 grid(HWSZ / BLKPX, N, NSPLIT);   // 128 x 4 x 2 = 1024 blocks
    mask_head_v16<<<grid, dim3(256), 0, stream>>>(x, params, nins, out, N, T);
}

// Round 17
// 27.308 us; speedup vs baseline: 1.4347x; 1.0147x over previous
//
#include <hip/hip_runtime.h>

// DynamicMaskHead v17: v14 structure exactly (single-launch, in-block param
// packing, stage-wise all-MFMA loop, verified absmax 0.046875), with:
//  - setprio removed (round-16 A/B: null),
//  - #pragma unroll 2 on the instance loop: static 2-iteration interleave
//    lets the scheduler hoist instance i+1's five ds_read_b128 under
//    instance i's MFMA/cvt tail WITH static register binding (the fix for
//    v15's runtime-selected-reference codegen collapse).
// Block = 4 waves x 80 px = 320 px; grid = 128 x 4 images x NSPLIT(2)
// = 1024 blocks = 4 blocks/CU; LDS 40960 B = 160 KiB/CU at 4 blocks.
// Per (instance, 16-px tile): 5 MFMAs, zero shuffles:
//   acc = ca*coords + W0a*X + W0b*X ; relu/cvt ; a1b MFMA (b1 channel);
//   relu/cvt ; a2r MFMA (row-replicated w2 + b2 channel) -> acc[0] = out.

#define CIN  64
#define HH   160
#define WW   256
#define HWSZ (HH * WW)
#define PP   1361
#define MASK_BIAS_SHIFT 2.19f
#define PKF  1280              // floats per instance in LDS block (5120 B)
#define NSPLIT 2               // instance split across gridDim.z
#define NT   5                 // 16-px tiles per wave (80 px)
#define MAXI 8                 // max instances per split (16 / NSPLIT)
#define BLKPX (16 * NT * 4)    // 320 px per block

typedef short short8 __attribute__((ext_vector_type(8)));
typedef float f32x4  __attribute__((ext_vector_type(4)));

union BF8 { short8 s; __bf16 b[8]; };

__device__ inline __bf16 bhi(float v) { return (__bf16)v; }
__device__ inline __bf16 blo(float v) { return (__bf16)(v - (float)(__bf16)v); }

// LDS float offsets per instance slot:
//   0: a00 (W0 x-ch 0..31)   256: a01 (x-ch 32..63)   512: a1b (W1 + b1 ch)
//   768: a2r (replicated w2 + b2 ch)   1024: ca (coord/b0 ch)

__device__ __forceinline__ void pack_one(const float* __restrict__ pw,
                                         int lane, float* __restrict__ dst)
{
    const int col = lane & 15;
    const int g   = lane >> 4;
    const __bf16 z = (__bf16)0.f;

    BF8 a00, a01;
#pragma unroll
    for (int j = 0; j < 8; ++j) {
        a00.b[j] = (__bf16)pw[col * 66 + 2 +      g * 8 + j];
        a01.b[j] = (__bf16)pw[col * 66 + 2 + 32 + g * 8 + j];
    }

    BF8 a1b;                                   // W1 (k=0..15) + b1 bias channel
#pragma unroll
    for (int j = 0; j < 4; ++j)
        a1b.b[j] = (__bf16)pw[1056 + col * 16 + g * 4 + j];
    {
        const float b1 = pw[1344 + col];
        a1b.b[4] = (g == 0) ? bhi(b1) : z;
        a1b.b[5] = (g == 0) ? blo(b1) : z;
        a1b.b[6] = z;  a1b.b[7] = z;
    }

    BF8 a2r;                    // w2 replicated across rows + b2 bias channel
#pragma unroll
    for (int j = 0; j < 4; ++j) a2r.b[j] = (__bf16)pw[1312 + g * 4 + j];
    {
        const float b2 = pw[1360] - MASK_BIAS_SHIFT;
        a2r.b[4] = (g == 0) ? bhi(b2) : z;
        a2r.b[5] = (g == 0) ? blo(b2) : z;
        a2r.b[6] = z;  a2r.b[7] = z;
    }

    BF8 ca;   // [wx_hi,wx_lo,wy_hi,wy_lo,b0_hi,b0_lo,0,0] on g==0 lanes
    {
        const float wx = pw[col * 66 + 0];
        const float wy = pw[col * 66 + 1];
        const float b0 = pw[1328 + col];
        ca.b[0] = (g == 0) ? bhi(wx) : z;
        ca.b[1] = (g == 0) ? blo(wx) : z;
        ca.b[2] = (g == 0) ? bhi(wy) : z;
        ca.b[3] = (g == 0) ? blo(wy) : z;
        ca.b[4] = (g == 0) ? bhi(b0) : z;
        ca.b[5] = (g == 0) ? blo(b0) : z;
        ca.b[6] = z; ca.b[7] = z;
    }

    ((short8*)(dst       ))[lane] = a00.s;
    ((short8*)(dst +  256))[lane] = a01.s;
    ((short8*)(dst +  512))[lane] = a1b.s;
    ((short8*)(dst +  768))[lane] = a2r.s;
    ((short8*)(dst + 1024))[lane] = ca.s;
}

__global__ __launch_bounds__(256, 4) void mask_head_v17(
    const float* __restrict__ x,
    const float* __restrict__ params,
    const int*   __restrict__ num_ins,
    float*       __restrict__ out,
    int N, int T)
{
    __shared__ __align__(16) float plds[MAXI][PKF];   // 40960 B

    const int tid  = threadIdx.x;
    const int wave = tid >> 6;
    const int lane = tid & 63;
    const int col  = lane & 15;
    const int g    = lane >> 4;
    const int n    = blockIdx.y;
    const int s    = blockIdx.z;
    const int pxw  = blockIdx.x * BLKPX + wave * (16 * NT);

    // instance range for this image (repeat-pad on last image)
    int t0 = 0;
    for (int j = 0; j < n; ++j) t0 += num_ins[j];
    int t1 = t0 + num_ins[n];
    if (n == N - 1) t1 = T;
    if (t1 > T) t1 = T;
    t0 = __builtin_amdgcn_readfirstlane(t0);
    t1 = __builtin_amdgcn_readfirstlane(t1);
    const int M = t1 - t0;

    // instances of this split: t = t0 + s + NSPLIT*i, i in [0, mloc)
    int mloc = (M - s + NSPLIT - 1) / NSPLIT;
    if (mloc < 0) mloc = 0;
    if (mloc > MAXI) mloc = MAXI;

    // ---- in-block packing: wave w packs instance slots {w, w+4}
#pragma unroll
    for (int k = 0; k < 2; ++k) {
        const int i = wave + k * 4;
        if (i < mloc) {
            const int t = t0 + s + NSPLIT * i;
            pack_one(params + (size_t)t * PP, lane, plds[i]);
        }
    }

    // x fragments: 80 px x 64 ch (40 VGPR); global-load latency overlaps
    // the packing (no LDS dependency until the barrier)
    BF8 xb[NT][2];
    const float* xbase = x + (size_t)n * CIN * HWSZ + pxw + col;
#pragma unroll
    for (int nt = 0; nt < NT; ++nt)
#pragma unroll
        for (int c = 0; c < 2; ++c)
#pragma unroll
            for (int j = 0; j < 8; ++j) {
                const int ch = c * 32 + g * 8 + j;
                xb[nt][c].b[j] = (__bf16)xbase[(size_t)ch * HWSZ + nt * 16];
            }

    // coordinate B-fragments (instance-independent): [xf,xf,yf,yf,1,1,0,0]
    BF8 b2c[NT];
#pragma unroll
    for (int nt = 0; nt < NT; ++nt) {
        const int px = pxw + nt * 16 + col;
        const __bf16 xfb = (__bf16)(float)(px & (WW - 1));
        const __bf16 yfb = (__bf16)(float)(px >> 8);
        b2c[nt].b[0] = xfb; b2c[nt].b[1] = xfb;
        b2c[nt].b[2] = yfb; b2c[nt].b[3] = yfb;
        b2c[nt].b[4] = (__bf16)1.f; b2c[nt].b[5] = (__bf16)1.f;
        b2c[nt].b[6] = (__bf16)0.f; b2c[nt].b[7] = (__bf16)0.f;
    }

    const __bf16 one = (__bf16)1.f, zero = (__bf16)0.f;
    __syncthreads();   // all packing visible

    // ---- instance loop: stage-wise tiles; unroll-2 interleaves the next
    // instance's ds_reads under this instance's MFMA/cvt tail (static regs)
#pragma unroll 2
    for (int i = 0; i < mloc; ++i) {
        const int t = t0 + s + NSPLIT * i;
        const short8* fp = (const short8*)plds[i];

        short8 ca  = fp[256 + lane];
        short8 a00 = fp[       lane];
        short8 a01 = fp[ 64 + lane];

        f32x4 acc[NT];
#pragma unroll
        for (int nt = 0; nt < NT; ++nt) {
            f32x4 z4 = {0.f, 0.f, 0.f, 0.f};
            acc[nt] = __builtin_amdgcn_mfma_f32_16x16x32_bf16(ca, b2c[nt].s, z4, 0, 0, 0);
        }
#pragma unroll
        for (int nt = 0; nt < NT; ++nt)
            acc[nt] = __builtin_amdgcn_mfma_f32_16x16x32_bf16(a00, xb[nt][0].s, acc[nt], 0, 0, 0);
#pragma unroll
        for (int nt = 0; nt < NT; ++nt)
            acc[nt] = __builtin_amdgcn_mfma_f32_16x16x32_bf16(a01, xb[nt][1].s, acc[nt], 0, 0, 0);

        BF8 h[NT];
#pragma unroll
        for (int nt = 0; nt < NT; ++nt) {
#pragma unroll
            for (int j = 0; j < 4; ++j) h[nt].b[j] = (__bf16)fmaxf(acc[nt][j], 0.f);
            h[nt].b[4] = one; h[nt].b[5] = one; h[nt].b[6] = zero; h[nt].b[7] = zero;
        }

        short8 a1b = fp[128 + lane];
#pragma unroll
        for (int nt = 0; nt < NT; ++nt) {
            f32x4 z4 = {0.f, 0.f, 0.f, 0.f};
            acc[nt] = __builtin_amdgcn_mfma_f32_16x16x32_bf16(a1b, h[nt].s, z4, 0, 0, 0);
        }

#pragma unroll
        for (int nt = 0; nt < NT; ++nt) {
#pragma unroll
            for (int j = 0; j < 4; ++j) h[nt].b[j] = (__bf16)fmaxf(acc[nt][j], 0.f);
            h[nt].b[4] = one; h[nt].b[5] = one; h[nt].b[6] = zero; h[nt].b[7] = zero;
        }

        short8 a2r = fp[192 + lane];
#pragma unroll
        for (int nt = 0; nt < NT; ++nt) {
            f32x4 z4 = {0.f, 0.f, 0.f, 0.f};
            acc[nt] = __builtin_amdgcn_mfma_f32_16x16x32_bf16(a2r, h[nt].s, z4, 0, 0, 0);
        }

        float oval = 0.f, t4 = 0.f;
#pragma unroll
        for (int nt = 0; nt < NT; ++nt) {
            if (nt == g)  oval = acc[nt][0];
            if (nt == 4)  t4   = acc[nt][0];
        }
        float* const op = out + (size_t)t * HWSZ + pxw;
        op[lane] = oval;                      // 64-lane coalesced (tiles 0-3)
        if (g == 0) op[64 + col] = t4;        // 16-lane store (tile 4)
    }
}

extern "C" void kernel_launch(void* const* d_in, const int* in_sizes, int n_in,
                              void* d_out, int out_size, void* d_ws, size_t ws_size,
                              hipStream_t stream) {
    const float* x      = (const float*)d_in[0];
    const float* params = (const float*)d_in[1];
    const int*   nins   = (const int*)d_in[2];
    float*       out    = (float*)d_out;

    const int N = in_sizes[2];            // images
    const int T = in_sizes[1] / PP;       // total instances (param rows)

    dim3 grid(HWSZ / BLKPX, N, NSPLIT);   // 128 x 4 x 2 = 1024 blocks
    mask_head_v17<<<grid, dim3(256), 0, stream>>>(x, params, nins, out, N, T);
}